// Round 4
// baseline (501.154 us; speedup 1.0000x reference)
//
#include <hip/hip_runtime.h>
#include <hip/hip_cooperative_groups.h>

namespace cg = cooperative_groups;

// Problem constants (match reference)
#define B 32
#define S 32
#define N 128
#define U 64
#define E 2
#define NCLS 5

// R11: single cooperative kernel. R7/R8/R9 (three different inner loops) all
// ~210us while per-step work accounts to ~12-15us -> the invariant ~100us is
// inter-dispatch overhead (7 serial launches of <35us kernels). Fuse all 6
// steps + final into ONE kernel with grid.sync() between steps (proper
// cooperative launch, not the R3/R4 hand-rolled cross-XCD atomics). Grid
// 512x256 = exactly 2 blocks/CU co-resident (launch_bounds(256,2) caps VGPR
// at 128, LDS 80B). Inner math is R9's verbatim -> bit-identical output.
//
// Each block: 8 rows of one batch (4 waves x 2 rows); lane = feature column.

__device__ __forceinline__ float sigmoid_f(float x) {
    return __fdividef(1.f, 1.f + __expf(-x));
}
__device__ __forceinline__ float tanh_f(float x) {
    float t = __expf(-2.f * fabsf(x));
    float y = __fdividef(1.f - t, 1.f + t);
    return copysignf(y, x);
}
// broadcast lane u's value of v to all lanes (VALU pipe, no LDS)
__device__ __forceinline__ float bcast(float v, int u) {
    return __uint_as_float(__builtin_amdgcn_readlane(__float_as_uint(v), u));
}

__global__ __launch_bounds__(256, 2) void k_fused(
    const float* __restrict__ x, const int* __restrict__ lens,
    float* __restrict__ hA, float* __restrict__ hB,
    const float* __restrict__ A, const float* __restrict__ Wmsg,
    const float* __restrict__ bmsg, const float* __restrict__ Wg,
    const float* __restrict__ Ug, const float* __restrict__ bg,
    const float* __restrict__ fcw, const float* __restrict__ fcb,
    float* __restrict__ partial, float* __restrict__ out) {
    cg::grid_group grid = cg::this_grid();
    __shared__ float red[4 * NCLS];
    int tid = threadIdx.x;
    int wave = tid >> 6, lane = tid & 63;
    int b = blockIdx.x >> 4;
    int j = blockIdx.x & 15;
    // wave-uniform row base; readfirstlane keeps A-row addresses scalar-provable
    int n0 = __builtin_amdgcn_readfirstlane(j * 8 + wave * 2);

    // x row used only by step 0
    int idx = lens[b] - 1;
    idx = idx < 0 ? 0 : (idx > S - 1 ? S - 1 : idx);
    const float* xsrc = x + (size_t)(b * S + idx) * N * U;

    const float4* A00 = (const float4*)(A + (((size_t)b * E + 0) * N + n0 + 0) * N);
    const float4* A10 = (const float4*)(A + (((size_t)b * E + 0) * N + n0 + 1) * N);
    const float4* A01 = (const float4*)(A + (((size_t)b * E + 1) * N + n0 + 0) * N);
    const float4* A11 = (const float4*)(A + (((size_t)b * E + 1) * N + n0 + 1) * N);

#pragma unroll 1
    for (int step = 0; step < 6; ++step) {
        int l = step >= 3 ? 1 : 0;
        // ping-pong: step0 x->hA, 1 hA->hB, 2 hB->hA, 3 hA->hB, 4 hB->hA, 5 hA->(partial)
        const float* hsrc = (step == 0) ? xsrc
                                        : ((step & 1) ? hA : hB) + (size_t)b * N * U;
        float* hdst = ((step & 1) ? hB : hA) + ((size_t)b * N + n0) * U;

        float hv0 = hsrc[(n0 + 0) * U + lane];
        float hv1 = hsrc[(n0 + 1) * U + lane];

        // ---- aggregate: s[row][e] = sum_m A[b,e,row,m] * h[m][lane]
        float s00 = 0.f, s01 = 0.f, s10 = 0.f, s11 = 0.f;
#pragma unroll 8
        for (int m4 = 0; m4 < N / 4; ++m4) {
            float4 a00 = A00[m4], a10 = A10[m4], a01 = A01[m4], a11 = A11[m4];
            float q0 = hsrc[(m4 * 4 + 0) * U + lane];
            float q1 = hsrc[(m4 * 4 + 1) * U + lane];
            float q2 = hsrc[(m4 * 4 + 2) * U + lane];
            float q3 = hsrc[(m4 * 4 + 3) * U + lane];
            s00 = fmaf(a00.x, q0, s00); s00 = fmaf(a00.y, q1, s00);
            s00 = fmaf(a00.z, q2, s00); s00 = fmaf(a00.w, q3, s00);
            s10 = fmaf(a10.x, q0, s10); s10 = fmaf(a10.y, q1, s10);
            s10 = fmaf(a10.z, q2, s10); s10 = fmaf(a10.w, q3, s10);
            s01 = fmaf(a01.x, q0, s01); s01 = fmaf(a01.y, q1, s01);
            s01 = fmaf(a01.z, q2, s01); s01 = fmaf(a01.w, q3, s01);
            s11 = fmaf(a11.x, q0, s11); s11 = fmaf(a11.y, q1, s11);
            s11 = fmaf(a11.z, q2, s11); s11 = fmaf(a11.w, q3, s11);
        }

        // ---- a[row] = sum_e s[row][e] @ Wmsg[l][e] + bmsg[l] (readlane bcast)
        float bm = bmsg[l * U + lane];
        float av0 = bm, av1 = bm;
        {
            const float* W0 = Wmsg + (size_t)(l * E + 0) * U * U + lane;
            const float* W1 = W0 + U * U;
#pragma unroll 16
            for (int u = 0; u < U; ++u) {
                float w = W0[u * U];
                av0 = fmaf(bcast(s00, u), w, av0);
                av1 = fmaf(bcast(s10, u), w, av1);
            }
#pragma unroll 16
            for (int u = 0; u < U; ++u) {
                float w = W1[u * U];
                av0 = fmaf(bcast(s01, u), w, av0);
                av1 = fmaf(bcast(s11, u), w, av1);
            }
        }

        // ---- gate matmuls (lane = output column v); a,h broadcast via readlane
        const float* Wg0 = Wg + (size_t)l * 3 * U * U + lane;
        const float* Wg1 = Wg0 + U * U;
        const float* Wg2 = Wg1 + U * U;
        const float* Ug0 = Ug + (size_t)l * 3 * U * U + lane;
        const float* Ug1 = Ug0 + U * U;
        const float* Ug2 = Ug1 + U * U;
        float accz0 = bg[(l * 3 + 0) * U + lane], accz1 = accz0;
        float accr0 = bg[(l * 3 + 1) * U + lane], accr1 = accr0;
        float accc0 = bg[(l * 3 + 2) * U + lane], accc1 = accc0;
#pragma unroll 16
        for (int u = 0; u < U; ++u) {
            float w0 = Wg0[u * U], w1 = Wg1[u * U], w2 = Wg2[u * U];
            float g0 = Ug0[u * U], g1 = Ug1[u * U];
            float a0 = bcast(av0, u), a1 = bcast(av1, u);
            float h0 = bcast(hv0, u), h1 = bcast(hv1, u);
            accz0 = fmaf(a0, w0, accz0); accz0 = fmaf(h0, g0, accz0);
            accz1 = fmaf(a1, w0, accz1); accz1 = fmaf(h1, g0, accz1);
            accr0 = fmaf(a0, w1, accr0); accr0 = fmaf(h0, g1, accr0);
            accr1 = fmaf(a1, w1, accr1); accr1 = fmaf(h1, g1, accr1);
            accc0 = fmaf(a0, w2, accc0);
            accc1 = fmaf(a1, w2, accc1);
        }
        float rg0 = sigmoid_f(accr0), rg1 = sigmoid_f(accr1);
        float rh0 = rg0 * hv0, rh1 = rg1 * hv1;
#pragma unroll 16
        for (int u = 0; u < U; ++u) {
            float g2 = Ug2[u * U];
            accc0 = fmaf(bcast(rh0, u), g2, accc0);
            accc1 = fmaf(bcast(rh1, u), g2, accc1);
        }
        float zg0 = sigmoid_f(accz0), zg1 = sigmoid_f(accz1);
        float hn0 = (1.f - zg0) * hv0 + zg0 * tanh_f(accc0);
        float hn1 = (1.f - zg1) * hv1 + zg1 * tanh_f(accc1);

        if (step < 5) {
            hdst[lane] = hn0;
            hdst[U + lane] = hn1;
        } else {
            // fused classification partial: max over our 8 rows of relu(h')@fc_w
            float lg0[NCLS], lg1[NCLS];
            float rv0 = hn0 > 0.f ? hn0 : 0.f;
            float rv1 = hn1 > 0.f ? hn1 : 0.f;
#pragma unroll
            for (int c = 0; c < NCLS; c++) {
                float w = fcw[lane * NCLS + c];
                lg0[c] = rv0 * w;
                lg1[c] = rv1 * w;
            }
#pragma unroll
            for (int off = 32; off; off >>= 1) {
#pragma unroll
                for (int c = 0; c < NCLS; c++) {
                    lg0[c] += __shfl_xor(lg0[c], off, 64);
                    lg1[c] += __shfl_xor(lg1[c], off, 64);
                }
            }
            if (lane == 0) {
#pragma unroll
                for (int c = 0; c < NCLS; c++) red[wave * NCLS + c] = fmaxf(lg0[c], lg1[c]);
            }
            __syncthreads();
            if (tid < NCLS) {
                float m = red[tid];
                for (int w = 1; w < 4; ++w) m = fmaxf(m, red[w * NCLS + tid]);
                partial[(size_t)(b * 16 + j) * NCLS + tid] = m;
            }
        }
        grid.sync();  // step barrier (device-scope fence included)
    }

    // ---- final: out[b][c] = max over 16 block-partials + fc_b
    if (blockIdx.x < B && tid < NCLS) {
        int bb = blockIdx.x, c = tid;
        float m = -3.4e38f;
        for (int jj = 0; jj < 16; ++jj)
            m = fmaxf(m, partial[(size_t)(bb * 16 + jj) * NCLS + c]);
        out[bb * NCLS + c] = m + fcb[c];
    }
}

// ---------------------------------------------------------------------------
extern "C" void kernel_launch(void* const* d_in, const int* in_sizes, int n_in,
                              void* d_out, int out_size, void* d_ws, size_t ws_size,
                              hipStream_t stream) {
    const float* x    = (const float*)d_in[0];
    const int*   lens = (const int*)d_in[1];
    const float* A    = (const float*)d_in[2];
    const float* Wmsg = (const float*)d_in[3];
    const float* bmsg = (const float*)d_in[4];
    const float* Wg   = (const float*)d_in[5];
    const float* Ug   = (const float*)d_in[6];
    const float* bg   = (const float*)d_in[7];
    const float* fcw  = (const float*)d_in[8];
    const float* fcb  = (const float*)d_in[9];
    float* out = (float*)d_out;

    float* hA      = (float*)d_ws;                   // [B][N][U]
    float* hB      = hA + (size_t)B * N * U;         // [B][N][U]
    float* partial = hB + (size_t)B * N * U;         // [B][16][NCLS]

    void* args[] = {(void*)&x, (void*)&lens, (void*)&hA, (void*)&hB,
                    (void*)&A, (void*)&Wmsg, (void*)&bmsg, (void*)&Wg,
                    (void*)&Ug, (void*)&bg, (void*)&fcw, (void*)&fcb,
                    (void*)&partial, (void*)&out};
    hipLaunchCooperativeKernel((const void*)k_fused, dim3(B * 16), dim3(256),
                               args, 0, stream);
}

// Round 5
// 224.536 us; speedup vs baseline: 2.2320x; 2.2320x over previous
//
#include <hip/hip_runtime.h>

// Problem constants (match reference)
#define B 32
#define S 32
#define N 128
#define U 64
#define E 2
#define NCLS 5

// R12: LDS-staged gate weights. R11 (cooperative) proved grid.sync ~40-55us
// (dead end) but exposed VALUBusy: only ~9us/step of VALU vs ~29us/step real
// -> steps are stall-bound. Cause: per-wave weight stream = 128KB/step but
// L1 = 32KB -> every weight load MISSES L1, served by L2 at ~200cyc, exposed
// at 2 waves/SIMD. Fix: stage Wg+Ug (96KB) in LDS per block (fixed ~60cyc,
// no thrash); Wmsg stays global so L2 and DS pipes split the serving. Shape:
// 512-thr blocks (8 waves x 2 rows = 16 rows), grid 256 = 1 block/CU -> same
// 8 waves/CU as the 209us best. Per-row FMA order identical -> bit-identical.

__device__ __forceinline__ float sigmoid_f(float x) {
    return __fdividef(1.f, 1.f + __expf(-x));
}
__device__ __forceinline__ float tanh_f(float x) {
    float t = __expf(-2.f * fabsf(x));
    float y = __fdividef(1.f - t, 1.f + t);
    return copysignf(y, x);
}
// broadcast lane u's value of v to all lanes (VALU pipe, no LDS)
__device__ __forceinline__ float bcast(float v, int u) {
    return __uint_as_float(__builtin_amdgcn_readlane(__float_as_uint(v), u));
}

template <int FIRST, int LAST>
__global__ __launch_bounds__(512, 2) void k_step(
    const float* __restrict__ x, const int* __restrict__ lens,
    const float* __restrict__ hin, float* __restrict__ hout,
    const float* __restrict__ A, const float* __restrict__ Wmsg,
    const float* __restrict__ bmsg, const float* __restrict__ Wg,
    const float* __restrict__ Ug, const float* __restrict__ bg,
    const float* __restrict__ fcw, float* __restrict__ partial, int l) {
    __shared__ float wgs[3 * U * U];  // 48 KB: Wg[l] staged
    __shared__ float ugs[3 * U * U];  // 48 KB: Ug[l] staged
    __shared__ float red[8 * NCLS];   // LAST tail reduce
    int tid = threadIdx.x;
    int wave = tid >> 6, lane = tid & 63;
    int b = blockIdx.x >> 3;
    int j = blockIdx.x & 7;
    // wave-uniform row base; readfirstlane keeps A-row addresses scalar-provable
    int n0 = __builtin_amdgcn_readfirstlane(j * 16 + wave * 2);

    // ---- stage gate weights into LDS (coalesced float4 copy, 6 iters/thread)
    {
        const float4* ws4 = (const float4*)(Wg + (size_t)l * 3 * U * U);
        const float4* us4 = (const float4*)(Ug + (size_t)l * 3 * U * U);
        float4* wd = (float4*)wgs;
        float4* ud = (float4*)ugs;
#pragma unroll
        for (int i = 0; i < 6; ++i) {
            wd[tid + i * 512] = ws4[tid + i * 512];
            ud[tid + i * 512] = us4[tid + i * 512];
        }
    }

    // h source: global (h[b]=32KB, L2-resident, shared by the batch's blocks)
    const float* __restrict__ hsrc;
    if (FIRST) {
        int idx = lens[b] - 1;
        idx = idx < 0 ? 0 : (idx > S - 1 ? S - 1 : idx);
        hsrc = x + (size_t)(b * S + idx) * N * U;
    } else {
        hsrc = hin + (size_t)b * N * U;
    }

    float hv0 = hsrc[(n0 + 0) * U + lane];
    float hv1 = hsrc[(n0 + 1) * U + lane];

    // ---- aggregate: s[row][e] = sum_m A[b,e,row,m] * h[m][lane]
    float s00 = 0.f, s01 = 0.f, s10 = 0.f, s11 = 0.f;
    {
        const float4* A00 = (const float4*)(A + (((size_t)b * E + 0) * N + n0 + 0) * N);
        const float4* A10 = (const float4*)(A + (((size_t)b * E + 0) * N + n0 + 1) * N);
        const float4* A01 = (const float4*)(A + (((size_t)b * E + 1) * N + n0 + 0) * N);
        const float4* A11 = (const float4*)(A + (((size_t)b * E + 1) * N + n0 + 1) * N);
#pragma unroll 8
        for (int m4 = 0; m4 < N / 4; ++m4) {
            float4 a00 = A00[m4], a10 = A10[m4], a01 = A01[m4], a11 = A11[m4];
            float q0 = hsrc[(m4 * 4 + 0) * U + lane];
            float q1 = hsrc[(m4 * 4 + 1) * U + lane];
            float q2 = hsrc[(m4 * 4 + 2) * U + lane];
            float q3 = hsrc[(m4 * 4 + 3) * U + lane];
            s00 = fmaf(a00.x, q0, s00); s00 = fmaf(a00.y, q1, s00);
            s00 = fmaf(a00.z, q2, s00); s00 = fmaf(a00.w, q3, s00);
            s10 = fmaf(a10.x, q0, s10); s10 = fmaf(a10.y, q1, s10);
            s10 = fmaf(a10.z, q2, s10); s10 = fmaf(a10.w, q3, s10);
            s01 = fmaf(a01.x, q0, s01); s01 = fmaf(a01.y, q1, s01);
            s01 = fmaf(a01.z, q2, s01); s01 = fmaf(a01.w, q3, s01);
            s11 = fmaf(a11.x, q0, s11); s11 = fmaf(a11.y, q1, s11);
            s11 = fmaf(a11.z, q2, s11); s11 = fmaf(a11.w, q3, s11);
        }
    }

    // ---- a[row] = sum_e s[row][e] @ Wmsg[l][e] + bmsg[l]  (global weights)
    float bm = bmsg[l * U + lane];
    float av0 = bm, av1 = bm;
    {
        const float* W0 = Wmsg + (size_t)(l * E + 0) * U * U + lane;
        const float* W1 = W0 + U * U;
#pragma unroll 16
        for (int u = 0; u < U; ++u) {
            float w = W0[u * U];
            av0 = fmaf(bcast(s00, u), w, av0);
            av1 = fmaf(bcast(s10, u), w, av1);
        }
#pragma unroll 16
        for (int u = 0; u < U; ++u) {
            float w = W1[u * U];
            av0 = fmaf(bcast(s01, u), w, av0);
            av1 = fmaf(bcast(s11, u), w, av1);
        }
    }

    __syncthreads();  // weights staged (placed late: staging latency hidden
                      // under aggregate+msg compute)

    // ---- gate matmuls from LDS (lane = output column v)
    const float* Wg0 = wgs + lane;
    const float* Wg1 = wgs + U * U + lane;
    const float* Wg2 = wgs + 2 * U * U + lane;
    const float* Ug0 = ugs + lane;
    const float* Ug1 = ugs + U * U + lane;
    const float* Ug2 = ugs + 2 * U * U + lane;
    float accz0 = bg[(l * 3 + 0) * U + lane], accz1 = accz0;
    float accr0 = bg[(l * 3 + 1) * U + lane], accr1 = accr0;
    float accc0 = bg[(l * 3 + 2) * U + lane], accc1 = accc0;
#pragma unroll 16
    for (int u = 0; u < U; ++u) {
        float w0 = Wg0[u * U], w1 = Wg1[u * U], w2 = Wg2[u * U];
        float g0 = Ug0[u * U], g1 = Ug1[u * U];
        float a0 = bcast(av0, u), a1 = bcast(av1, u);
        float h0 = bcast(hv0, u), h1 = bcast(hv1, u);
        accz0 = fmaf(a0, w0, accz0); accz0 = fmaf(h0, g0, accz0);
        accz1 = fmaf(a1, w0, accz1); accz1 = fmaf(h1, g0, accz1);
        accr0 = fmaf(a0, w1, accr0); accr0 = fmaf(h0, g1, accr0);
        accr1 = fmaf(a1, w1, accr1); accr1 = fmaf(h1, g1, accr1);
        accc0 = fmaf(a0, w2, accc0);
        accc1 = fmaf(a1, w2, accc1);
    }
    float rg0 = sigmoid_f(accr0), rg1 = sigmoid_f(accr1);
    float rh0 = rg0 * hv0, rh1 = rg1 * hv1;
#pragma unroll 16
    for (int u = 0; u < U; ++u) {
        float g2 = Ug2[u * U];
        accc0 = fmaf(bcast(rh0, u), g2, accc0);
        accc1 = fmaf(bcast(rh1, u), g2, accc1);
    }
    float zg0 = sigmoid_f(accz0), zg1 = sigmoid_f(accz1);
    float hn0 = (1.f - zg0) * hv0 + zg0 * tanh_f(accc0);
    float hn1 = (1.f - zg1) * hv1 + zg1 * tanh_f(accc1);

    if (!LAST) {
        hout[((size_t)b * N + n0 + 0) * U + lane] = hn0;
        hout[((size_t)b * N + n0 + 1) * U + lane] = hn1;
    } else {
        // fused classification partial: max over our 16 rows of relu(h')@fc_w
        float lg0[NCLS], lg1[NCLS];
        float rv0 = hn0 > 0.f ? hn0 : 0.f;
        float rv1 = hn1 > 0.f ? hn1 : 0.f;
#pragma unroll
        for (int c = 0; c < NCLS; c++) {
            float w = fcw[lane * NCLS + c];
            lg0[c] = rv0 * w;
            lg1[c] = rv1 * w;
        }
#pragma unroll
        for (int off = 32; off; off >>= 1) {
#pragma unroll
            for (int c = 0; c < NCLS; c++) {
                lg0[c] += __shfl_xor(lg0[c], off, 64);
                lg1[c] += __shfl_xor(lg1[c], off, 64);
            }
        }
        if (lane == 0) {
#pragma unroll
            for (int c = 0; c < NCLS; c++) red[wave * NCLS + c] = fmaxf(lg0[c], lg1[c]);
        }
        __syncthreads();
        if (tid < NCLS) {
            float m = red[tid];
            for (int w = 1; w < 8; ++w) m = fmaxf(m, red[w * NCLS + tid]);
            partial[(size_t)(b * 8 + j) * NCLS + tid] = m;
        }
    }
}

// ---------------------------------------------------------------------------
// k_final: out[b][c] = max over 8 block-partials + fc_b
__global__ void k_final(const float* __restrict__ partial, const float* __restrict__ fcb,
                        float* __restrict__ out) {
    int b = blockIdx.x, c = threadIdx.x;
    if (c < NCLS) {
        float m = -3.4e38f;
        for (int jj = 0; jj < 8; ++jj)
            m = fmaxf(m, partial[(size_t)(b * 8 + jj) * NCLS + c]);
        out[b * NCLS + c] = m + fcb[c];
    }
}

// ---------------------------------------------------------------------------
extern "C" void kernel_launch(void* const* d_in, const int* in_sizes, int n_in,
                              void* d_out, int out_size, void* d_ws, size_t ws_size,
                              hipStream_t stream) {
    const float* x    = (const float*)d_in[0];
    const int*   lens = (const int*)d_in[1];
    const float* A    = (const float*)d_in[2];
    const float* Wmsg = (const float*)d_in[3];
    const float* bmsg = (const float*)d_in[4];
    const float* Wg   = (const float*)d_in[5];
    const float* Ug   = (const float*)d_in[6];
    const float* bg   = (const float*)d_in[7];
    const float* fcw  = (const float*)d_in[8];
    const float* fcb  = (const float*)d_in[9];
    float* out = (float*)d_out;

    float* hA      = (float*)d_ws;                   // [B][N][U]
    float* hB      = hA + (size_t)B * N * U;         // [B][N][U]
    float* partial = hB + (size_t)B * N * U;         // [B][8][NCLS]

    // steps 0-2: layer 0; steps 3-5: layer 1
    k_step<1, 0><<<B * 8, 512, 0, stream>>>(x, lens, nullptr, hA, A, Wmsg, bmsg, Wg, Ug, bg, fcw, partial, 0);
    k_step<0, 0><<<B * 8, 512, 0, stream>>>(x, lens, hA, hB, A, Wmsg, bmsg, Wg, Ug, bg, fcw, partial, 0);
    k_step<0, 0><<<B * 8, 512, 0, stream>>>(x, lens, hB, hA, A, Wmsg, bmsg, Wg, Ug, bg, fcw, partial, 0);
    k_step<0, 0><<<B * 8, 512, 0, stream>>>(x, lens, hA, hB, A, Wmsg, bmsg, Wg, Ug, bg, fcw, partial, 1);
    k_step<0, 0><<<B * 8, 512, 0, stream>>>(x, lens, hB, hA, A, Wmsg, bmsg, Wg, Ug, bg, fcw, partial, 1);
    k_step<0, 1><<<B * 8, 512, 0, stream>>>(x, lens, hA, hB, A, Wmsg, bmsg, Wg, Ug, bg, fcw, partial, 1);
    k_final<<<B, 64, 0, stream>>>(partial, fcb, out);
}